// Round 5
// baseline (308.264 us; speedup 1.0000x reference)
//
#include <hip/hip_runtime.h>
#include <math.h>

#define B_   16
#define N_   16384
#define H_   8192      // N/2
#define LOGH 13
#define CIN  64
#define COUT 64
#define T_   256
#define M_   2049

__device__ __forceinline__ unsigned br13(unsigned v) {
  return __brev(v) >> 19;   // 13-bit reversal
}

// XOR bank swizzle: bank(n) = (n ^ n>>5 ^ n>>10) & 31. Bijective per 32-block.
__device__ __forceinline__ int SW(int n) {
  return (n & ~31) | ((n ^ (n >> 5) ^ (n >> 10)) & 31);
}

__device__ __forceinline__ void cmul(float ar, float ai, float br, float bi,
                                     float& rr, float& ri) {
  rr = ar * br - ai * bi;
  ri = ar * bi + ai * br;
}

// cos/sin of 2*pi*m/16
__device__ __constant__ float C16[16] = {
  1.f, 0.92387953251f, 0.70710678119f, 0.38268343236f, 0.f, -0.38268343236f,
  -0.70710678119f, -0.92387953251f, -1.f, -0.92387953251f, -0.70710678119f,
  -0.38268343236f, 0.f, 0.38268343236f, 0.70710678119f, 0.92387953251f};
__device__ __constant__ float S16[16] = {
  0.f, 0.38268343236f, 0.70710678119f, 0.92387953251f, 1.f, 0.92387953251f,
  0.70710678119f, 0.38268343236f, 0.f, -0.38268343236f, -0.70710678119f,
  -0.92387953251f, -1.f, -0.92387953251f, -0.70710678119f, -0.38268343236f};

// One radix-16 group = 4 radix-2 DIT substages done in registers.
template <int SIGN, int S0>
__device__ __forceinline__ void group16(float* __restrict__ sre,
                                        float* __restrict__ sim, int tid) {
  const int lo = tid & ((1 << S0) - 1);
  const int hi = tid >> S0;
  const int base = (hi << (S0 + 4)) + lo;
  int pp[16];
  float xr[16], xi[16];
#pragma unroll
  for (int j = 0; j < 16; ++j) {
    pp[j] = SW(base + (j << S0));
    xr[j] = sre[pp[j]];
    xi[j] = sim[pp[j]];
  }
  float th = 6.283185307179586f * (float)lo / (float)(16 << S0);
  float sn, cs;
  __sincosf(th, &sn, &cs);
  float w1r = cs, w1i = (float)SIGN * sn;
  float w2r, w2i, w4r, w4i, w8r, w8i;
  cmul(w1r, w1i, w1r, w1i, w2r, w2i);
  cmul(w2r, w2i, w2r, w2i, w4r, w4i);
  cmul(w4r, w4i, w4r, w4i, w8r, w8i);
  {
#pragma unroll
    for (int j = 0; j < 16; j += 2) {
      float br, bi;
      cmul(xr[j + 1], xi[j + 1], w8r, w8i, br, bi);
      xr[j + 1] = xr[j] - br; xi[j + 1] = xi[j] - bi;
      xr[j] += br; xi[j] += bi;
    }
  }
  {
    float tr[2], ti[2];
    tr[0] = w4r; ti[0] = w4i;
    cmul(w4r, w4i, C16[4], (float)SIGN * S16[4], tr[1], ti[1]);
#pragma unroll
    for (int j = 0; j < 16; ++j) {
      if ((j & 2) == 0) {
        int jl = j & 1;
        float br, bi;
        cmul(xr[j + 2], xi[j + 2], tr[jl], ti[jl], br, bi);
        xr[j + 2] = xr[j] - br; xi[j + 2] = xi[j] - bi;
        xr[j] += br; xi[j] += bi;
      }
    }
  }
  {
    float tr[4], ti[4];
#pragma unroll
    for (int jl = 0; jl < 4; ++jl)
      cmul(w2r, w2i, C16[2 * jl], (float)SIGN * S16[2 * jl], tr[jl], ti[jl]);
#pragma unroll
    for (int j = 0; j < 16; ++j) {
      if ((j & 4) == 0) {
        int jl = j & 3;
        float br, bi;
        cmul(xr[j + 4], xi[j + 4], tr[jl], ti[jl], br, bi);
        xr[j + 4] = xr[j] - br; xi[j + 4] = xi[j] - bi;
        xr[j] += br; xi[j] += bi;
      }
    }
  }
  {
    float tr[8], ti[8];
#pragma unroll
    for (int jl = 0; jl < 8; ++jl)
      cmul(w1r, w1i, C16[jl], (float)SIGN * S16[jl], tr[jl], ti[jl]);
#pragma unroll
    for (int j = 0; j < 8; ++j) {
      float br, bi;
      cmul(xr[j + 8], xi[j + 8], tr[j], ti[j], br, bi);
      xr[j + 8] = xr[j] - br; xi[j + 8] = xi[j] - bi;
      xr[j] += br; xi[j] += bi;
    }
  }
#pragma unroll
  for (int j = 0; j < 16; ++j) {
    sre[pp[j]] = xr[j];
    sim[pp[j]] = xi[j];
  }
}

// Final radix-2 stage (lh=12): pairs (n, n+4096).
template <int SIGN>
__device__ __forceinline__ void stageD(float* __restrict__ sre,
                                       float* __restrict__ sim, int tid) {
  float th = 6.283185307179586f * (float)tid / 8192.0f;
  float sn, cs;
  __sincosf(th, &sn, &cs);
  float wtr = cs, wti = (float)SIGN * sn;
#pragma unroll
  for (int s = 0; s < 8; ++s) {
    float twr, twi;
    cmul(wtr, wti, C16[s], (float)SIGN * S16[s], twr, twi);
    int i0 = tid + 512 * s;
    int p0 = SW(i0), p1 = SW(i0 + 4096);
    float br, bi;
    cmul(sre[p1], sim[p1], twr, twi, br, bi);
    float ar = sre[p0], ai = sim[p0];
    sre[p0] = ar + br; sim[p0] = ai + bi;
    sre[p1] = ar - br; sim[p1] = ai - bi;
  }
}

// ---------------- Kernel A: t_mod = t_emb @ dense^T (complex) ----------------
__global__ __launch_bounds__(256) void tmod_kernel(
    const float* __restrict__ t_emb,
    const float* __restrict__ dwr, const float* __restrict__ dwi,
    float* __restrict__ tmr, float* __restrict__ tmi) {
  int wave = threadIdx.x >> 6;
  int lane = threadIdx.x & 63;
  int p = blockIdx.x * 4 + wave;
  if (p >= B_ * M_) return;
  int b = p / M_, i = p % M_;
  float ar = 0.f, ai = 0.f;
  for (int j = 0; j < 4; ++j) {
    int t = lane + 64 * j;
    float te = t_emb[b * T_ + t];
    ar += te * dwr[(size_t)i * T_ + t];
    ai += te * dwi[(size_t)i * T_ + t];
  }
  for (int off = 32; off > 0; off >>= 1) {
    ar += __shfl_down(ar, off, 64);
    ai += __shfl_down(ai, off, 64);
  }
  if (lane == 0) { tmr[b * M_ + i] = ar; tmi[b * M_ + i] = ai; }
}

// ------- Kernel T1: x (B,N,C) -> packed complex planes z (B*C, H) ------------
__global__ __launch_bounds__(256) void pack_transpose(
    const float* __restrict__ x, float* __restrict__ zre, float* __restrict__ zim) {
  __shared__ float tile[64][65];
  int b = blockIdx.y, nt = blockIdx.x;
  int n0 = nt * 64;
  int j  = threadIdx.x & 63;
  int iy = threadIdx.x >> 6;
  for (int p = 0; p < 16; ++p) {
    int i = iy + 4 * p;
    tile[i][j] = x[((size_t)(b * N_ + n0 + i)) * CIN + j];
  }
  __syncthreads();
  int ii = threadIdx.x & 31;
  int cy = threadIdx.x >> 5;
  int h0 = nt * 32;
  for (int p = 0; p < 8; ++p) {
    int c = cy + 8 * p;
    size_t o = (size_t)(b * CIN + c) * H_ + h0 + ii;
    zre[o] = tile[2 * ii][c];
    zim[o] = tile[2 * ii + 1][c];
  }
}

// ---------------- Kernel B: forward FFT + rfft split, writes (k, bc) ---------
__global__ __launch_bounds__(512, 4) void fft_fwd(
    const float* __restrict__ zre, const float* __restrict__ zim,
    float* __restrict__ Xtr, float* __restrict__ Xti) {
  __shared__ float sre[H_], sim[H_];
  int hw = blockIdx.x;
  int bc = ((hw & 7) << 7) | (hw >> 3);
  int tid = threadIdx.x;
  size_t base = (size_t)bc * H_;
#pragma unroll
  for (int s = 0; s < 16; ++s) {
    int n = tid + 512 * s;
    int r = SW((int)br13(n));
    sre[r] = zre[base + n];
    sim[r] = zim[base + n];
  }
  __syncthreads();
  group16<-1, 0>(sre, sim, tid); __syncthreads();
  group16<-1, 4>(sre, sim, tid); __syncthreads();
  group16<-1, 8>(sre, sim, tid); __syncthreads();
  stageD<-1>(sre, sim, tid);     __syncthreads();
  const float sc = 1.0f / (float)N_;
  for (int k = tid; k < M_; k += 512) {
    int mk = (H_ - k) & (H_ - 1);
    int pk = SW(k), pm = SW(mk);
    float zr = sre[pk], zi = sim[pk];
    float mr = sre[pm], mi = -sim[pm];
    float Er = 0.5f * (zr + mr), Ei = 0.5f * (zi + mi);
    float Dr = zr - mr,          Di = zi - mi;
    float Or = 0.5f * Di,        Oi = -0.5f * Dr;
    float ang = -6.283185307179586f * (float)k / (float)N_;
    float sn, cs;
    __sincosf(ang, &sn, &cs);
    float Xr = Er + cs * Or - sn * Oi;
    float Xi = Ei + cs * Oi + sn * Or;
    Xtr[(size_t)k * 1024 + bc] = Xr * sc;
    Xti[(size_t)k * 1024 + bc] = Xi * sc;
  }
}

// ---------------- Kernel C: per-frequency channel mix via MFMA (bf16x3) ------
// One WAVE per frequency i. No LDS, no barriers. Register-only fragments.
// Y[i,b,o] = tmod[b,i] * sum_c X[i,b,c]*W[i,c,o]; writes Yt (bo, k) layout.
// Fragment layouts (16x16x32 bf16, verified m89/m120):
//   A: lane L holds A[m=L&15][k=(L>>4)*8+j]   j=0..7
//   B: lane L holds B[k=(L>>4)*8+j][n=L&15]
//   C/D: lane L holds D[m=(L>>4)*4+r][n=L&15] r=0..3
typedef short  s8v  __attribute__((ext_vector_type(8)));
typedef float  f4v  __attribute__((ext_vector_type(4)));

__device__ __forceinline__ unsigned short f2bf_hi(float x) {
  unsigned u = __float_as_uint(x);
  unsigned r = (u + 0x7fffu + ((u >> 16) & 1u)) >> 16;   // RNE
  return (unsigned short)r;
}
__device__ __forceinline__ void cvt8(const float* v, s8v& h, s8v& l) {
#pragma unroll
  for (int e = 0; e < 8; ++e) {
    unsigned short hh = f2bf_hi(v[e]);
    float hf = __uint_as_float(((unsigned)hh) << 16);
    h[e] = (short)hh;
    l[e] = (short)f2bf_hi(v[e] - hf);
  }
}

__global__ __launch_bounds__(256) void mix_mfma(
    const float* __restrict__ Xtr, const float* __restrict__ Xti,
    const float* __restrict__ Wr_g, const float* __restrict__ Wi_g,
    const float* __restrict__ tmr, const float* __restrict__ tmi,
    float* __restrict__ Ytr, float* __restrict__ Yti) {
  const int hw = blockIdx.x;
  const int w  = threadIdx.x >> 6, L = threadIdx.x & 63;
  const int il = (hw >> 3) * 4 + w;          // local i within this XCD's run
  if (il >= 257) return;
  const int i = (hw & 7) * 257 + il;         // XCD-local runs of 257
  if (i >= M_) return;
  const int q = L >> 4, mlane = L & 15;

  // --- A fragments from Xt row (contiguous 8 floats per slab) ---
  s8v arh[2], arl[2], aih[2], ail[2], anh[2], anl[2];
#pragma unroll
  for (int s = 0; s < 2; ++s) {
    const float* xr = Xtr + (size_t)i * 1024 + mlane * 64 + q * 8 + 32 * s;
    const float* xi = Xti + (size_t)i * 1024 + mlane * 64 + q * 8 + 32 * s;
    float ar[8], ai_[8];
    *(float4*)(ar)      = *(const float4*)(xr);
    *(float4*)(ar + 4)  = *(const float4*)(xr + 4);
    *(float4*)(ai_)     = *(const float4*)(xi);
    *(float4*)(ai_ + 4) = *(const float4*)(xi + 4);
    cvt8(ar, arh[s], arl[s]);
    cvt8(ai_, aih[s], ail[s]);
#pragma unroll
    for (int e = 0; e < 8; ++e) {
      anh[s][e] = (short)(((unsigned short)aih[s][e]) ^ 0x8000u);
      anl[s][e] = (short)(((unsigned short)ail[s][e]) ^ 0x8000u);
    }
  }
  // --- t_mod for this lane's 4 output rows ---
  float trm[4], tim_[4];
#pragma unroll
  for (int r = 0; r < 4; ++r) {
    int m = q * 4 + r;
    trm[r]  = tmr[m * M_ + i];
    tim_[r] = tmi[m * M_ + i];
  }

#pragma unroll
  for (int nt = 0; nt < 4; ++nt) {
    const int n = mlane + 16 * nt;
    f4v cr = {0.f, 0.f, 0.f, 0.f}, ci = {0.f, 0.f, 0.f, 0.f};
#pragma unroll
    for (int s = 0; s < 2; ++s) {
      const float* wrp = Wr_g + (size_t)i * 4096 + (q * 8 + 32 * s) * 64 + n;
      const float* wip = Wi_g + (size_t)i * 4096 + (q * 8 + 32 * s) * 64 + n;
      float brf[8], bif[8];
#pragma unroll
      for (int j = 0; j < 8; ++j) {
        brf[j] = wrp[j * 64];
        bif[j] = wip[j * 64];
      }
      s8v brh, brl, bih, bil;
      cvt8(brf, brh, brl);
      cvt8(bif, bih, bil);
      cr = __builtin_amdgcn_mfma_f32_16x16x32_bf16(arh[s], brh, cr, 0, 0, 0);
      cr = __builtin_amdgcn_mfma_f32_16x16x32_bf16(arh[s], brl, cr, 0, 0, 0);
      cr = __builtin_amdgcn_mfma_f32_16x16x32_bf16(arl[s], brh, cr, 0, 0, 0);
      cr = __builtin_amdgcn_mfma_f32_16x16x32_bf16(anh[s], bih, cr, 0, 0, 0);
      cr = __builtin_amdgcn_mfma_f32_16x16x32_bf16(anh[s], bil, cr, 0, 0, 0);
      cr = __builtin_amdgcn_mfma_f32_16x16x32_bf16(anl[s], bih, cr, 0, 0, 0);
      ci = __builtin_amdgcn_mfma_f32_16x16x32_bf16(arh[s], bih, ci, 0, 0, 0);
      ci = __builtin_amdgcn_mfma_f32_16x16x32_bf16(arh[s], bil, ci, 0, 0, 0);
      ci = __builtin_amdgcn_mfma_f32_16x16x32_bf16(arl[s], bih, ci, 0, 0, 0);
      ci = __builtin_amdgcn_mfma_f32_16x16x32_bf16(aih[s], brh, ci, 0, 0, 0);
      ci = __builtin_amdgcn_mfma_f32_16x16x32_bf16(aih[s], brl, ci, 0, 0, 0);
      ci = __builtin_amdgcn_mfma_f32_16x16x32_bf16(ail[s], brh, ci, 0, 0, 0);
    }
#pragma unroll
    for (int r = 0; r < 4; ++r) {
      int m = q * 4 + r;
      float yr = trm[r] * cr[r] - tim_[r] * ci[r];
      float yi = trm[r] * ci[r] + tim_[r] * cr[r];
      size_t o = (size_t)(m * 64 + n) * M_ + i;
      Ytr[o] = yr;
      Yti[o] = yi;
    }
  }
}

// ---------------- Kernel D: inverse packing + inverse FFT --------------------
__global__ __launch_bounds__(512, 4) void fft_inv(
    const float* __restrict__ Ytr, const float* __restrict__ Yti,
    float* __restrict__ zre, float* __restrict__ zim) {
  __shared__ float sre[H_], sim[H_];
  int bo = blockIdx.x;
  int tid = threadIdx.x;
  size_t ybase = (size_t)bo * M_;
#pragma unroll
  for (int s = 0; s < 16; ++s) {
    int k = tid + 512 * s;
    float ykr = 0.f, yki = 0.f, ymr = 0.f, ymi = 0.f;
    if (k < M_) { ykr = Ytr[ybase + k]; yki = Yti[ybase + k]; }
    int m = H_ - k;
    if (m < M_) { ymr = Ytr[ybase + m]; ymi = -Yti[ybase + m]; }
    float Sr = ykr + ymr, Si = yki + ymi;
    float Dr = ykr - ymr, Di = yki - ymi;
    float ang = 6.283185307179586f * (float)k / (float)N_;
    float sn, cs;
    __sincosf(ang, &sn, &cs);
    float Zr = Sr - (cs * Di + sn * Dr);
    float Zi = Si + (cs * Dr - sn * Di);
    int r = SW((int)br13(k));
    sre[r] = Zr; sim[r] = Zi;
  }
  __syncthreads();
  group16<1, 0>(sre, sim, tid); __syncthreads();
  group16<1, 4>(sre, sim, tid); __syncthreads();
  group16<1, 8>(sre, sim, tid); __syncthreads();
  stageD<1>(sre, sim, tid);     __syncthreads();
  size_t base = (size_t)bo * H_;
#pragma unroll
  for (int s = 0; s < 16; ++s) {
    int n = tid + 512 * s;
    int p = SW(n);
    zre[base + n] = sre[p];
    zim[base + n] = sim[p];
  }
}

// ------- Kernel T4: z planes (B*Cout, H) -> out (B, N, Cout) -----------------
__global__ __launch_bounds__(256) void unpack_transpose(
    const float* __restrict__ zre, const float* __restrict__ zim,
    float* __restrict__ out) {
  __shared__ float tre[64][33], tim[64][33];
  int b = blockIdx.y, ht = blockIdx.x;
  int h0 = ht * 32;
  int ii = threadIdx.x & 31, cy = threadIdx.x >> 5;
  for (int p = 0; p < 8; ++p) {
    int c = cy + 8 * p;
    size_t idx = (size_t)(b * COUT + c) * H_ + h0 + ii;
    tre[c][ii] = zre[idx];
    tim[c][ii] = zim[idx];
  }
  __syncthreads();
  int o = threadIdx.x & 63, ry = threadIdx.x >> 6;
  for (int p = 0; p < 16; ++p) {
    int r = ry + 4 * p;
    int n = h0 * 2 + r;
    float v = (r & 1) ? tim[o][r >> 1] : tre[o][r >> 1];
    out[((size_t)(b * N_ + n)) * COUT + o] = v;
  }
}

extern "C" void kernel_launch(void* const* d_in, const int* in_sizes, int n_in,
                              void* d_out, int out_size, void* d_ws, size_t ws_size,
                              hipStream_t stream) {
  const float* x    = (const float*)d_in[0];
  const float* temb = (const float*)d_in[1];
  const float* wr   = (const float*)d_in[2];
  const float* wi   = (const float*)d_in[3];
  const float* dwr  = (const float*)d_in[4];
  const float* dwi  = (const float*)d_in[5];
  float* out = (float*)d_out;

  float* ws  = (float*)d_ws;
  float* tmr = ws;
  float* tmi = tmr + 32784;
  float* zre = tmi + 32784;                // (B*C, H) — reused by inverse
  float* zim = zre + 8388608;
  float* Xtr = zim + 8388608;              // Xt (k, bc) from fft_fwd
  float* Xti = Xtr + 2098176;
  float* Ytr = Xti + 2098176;              // Yt (bc, k) from mix
  float* Yti = Ytr + 2098176;

  tmod_kernel<<<dim3((B_ * M_ + 3) / 4), 256, 0, stream>>>(temb, dwr, dwi, tmr, tmi);
  pack_transpose<<<dim3(N_ / 64, B_), 256, 0, stream>>>(x, zre, zim);
  fft_fwd<<<dim3(B_ * CIN), 512, 0, stream>>>(zre, zim, Xtr, Xti);
  mix_mfma<<<dim3(520), 256, 0, stream>>>(Xtr, Xti, wr, wi, tmr, tmi, Ytr, Yti);
  fft_inv<<<dim3(B_ * COUT), 512, 0, stream>>>(Ytr, Yti, zre, zim);
  unpack_transpose<<<dim3(H_ / 32, B_), 256, 0, stream>>>(zre, zim, out);
}